// Round 2
// baseline (1258.538 us; speedup 1.0000x reference)
//
#include <hip/hip_runtime.h>

typedef unsigned int uint;
typedef unsigned short ushort;

typedef __attribute__((ext_vector_type(8))) short sh8;
typedef __attribute__((ext_vector_type(4))) float f32x4;

__device__ __forceinline__ ushort f2b(float f) {
    uint x = __float_as_uint(f);
    x += 0x7fffu + ((x >> 16) & 1u);
    return (ushort)(x >> 16);
}
__device__ __forceinline__ float b2f(ushort u) {
    return __uint_as_float(((uint)u) << 16);
}
__device__ __forceinline__ uint pack2(float a, float b) {
    return (uint)f2b(a) | ((uint)f2b(b) << 16);
}
__device__ __forceinline__ float frcp(float x) { return __builtin_amdgcn_rcpf(x); }
// saturating via inf: exp(+inf)->inf -> rcp -> 0, no clamps needed
__device__ __forceinline__ float sigmf(float x) { return frcp(1.0f + __expf(-x)); }
__device__ __forceinline__ float tanhf2(float y) {
    return fmaf(2.0f, frcp(1.0f + __expf(-2.0f * y)), -1.0f);
}

// ---------------------------------------------------------------------------
// Index-width detector for x (robustness; x believed int32).
// ---------------------------------------------------------------------------
__global__ __launch_bounds__(256) void k_detx(const uint* __restrict__ xw,
                                              int* __restrict__ flag) {
    __shared__ int sh[256];
    int t = threadIdx.x;
    int c = 0;
    for (int i = t; i < 2048; i += 256) c += (xw[2 * i + 1] == 0u) ? 1 : 0;
    sh[t] = c;
    __syncthreads();
    if (t == 0) {
        int s = 0;
        for (int i = 0; i < 256; i++) s += sh[i];
        flag[0] = (s >= 1843) ? 1 : 0;  // >=90% zeros -> int64
    }
}

// ---------------------------------------------------------------------------
// Embedding gather, fp32 -> bf16, index-width aware.
// ---------------------------------------------------------------------------
__global__ __launch_bounds__(256) void k_gather(const void* __restrict__ x,
                                                const float* __restrict__ embed,
                                                const int* __restrict__ flag,
                                                ushort* __restrict__ out) {
    int chunk = blockIdx.x * 256 + threadIdx.x;
    int row = chunk >> 5;
    int c = chunk & 31;
    int v;
    if (flag[0]) {
        v = (int)((const uint*)x)[2 * row];
    } else {
        v = ((const int*)x)[row];
    }
    v = min(max(v, 0), 49999);
    const float4* e = (const float4*)&embed[(size_t)v * 256 + (size_t)c * 8];
    float4 a = e[0], b = e[1];
    uint4 pv;
    pv.x = pack2(a.x, a.y);
    pv.y = pack2(a.z, a.w);
    pv.z = pack2(b.x, b.y);
    pv.w = pack2(b.z, b.w);
    *(uint4*)&out[(size_t)row * 256 + (size_t)c * 8] = pv;
}

// ---------------------------------------------------------------------------
// GEMM (unchanged, verified): C = A(bf16) * W^T(fp32 inline->bf16) + bias,
// optional GELU; bf16 Cb and/or fp32 Cf outputs.
// ---------------------------------------------------------------------------
__global__ __launch_bounds__(256) void k_gemm_bt(const ushort* __restrict__ A,
                                                 const float* __restrict__ Wf,
                                                 const float* __restrict__ bias,
                                                 ushort* __restrict__ Cb,
                                                 float* __restrict__ Cf,
                                                 int M, int N, int K, int gelu) {
    __shared__ __align__(16) ushort Al[128 * 32];
    __shared__ __align__(16) ushort Bl[128 * 32];
    int tid = threadIdx.x;
    int bm = blockIdx.x, bn = blockIdx.y;
    int wid = tid >> 6, lane = tid & 63;
    int ln = lane & 15, kq = lane >> 4;
    int wm = (wid & 1) * 64, wn = (wid >> 1) * 64;
    int rowA0 = bm * 128, rowB0 = bn * 128;

    f32x4 acc[4][4];
#pragma unroll
    for (int i = 0; i < 4; i++)
#pragma unroll
        for (int j = 0; j < 4; j++) acc[i][j] = (f32x4){0.f, 0.f, 0.f, 0.f};

    for (int kt = 0; kt < K; kt += 32) {
#pragma unroll
        for (int c = tid; c < 512; c += 256) {
            int r = c >> 2, c8 = (c & 3) * 8;
            *(uint4*)&Al[r * 32 + c8] =
                *(const uint4*)&A[(size_t)(rowA0 + r) * K + kt + c8];
            int nb = rowB0 + r;
            uint4 bv = {0u, 0u, 0u, 0u};
            if (nb < N) {
                const float4* wp = (const float4*)&Wf[(size_t)nb * K + kt + c8];
                float4 w0 = wp[0], w1 = wp[1];
                bv.x = pack2(w0.x, w0.y);
                bv.y = pack2(w0.z, w0.w);
                bv.z = pack2(w1.x, w1.y);
                bv.w = pack2(w1.z, w1.w);
            }
            *(uint4*)&Bl[r * 32 + c8] = bv;
        }
        __syncthreads();
        sh8 af[4], bfr[4];
#pragma unroll
        for (int i = 0; i < 4; i++)
            af[i] = *(const sh8*)&Al[(wm + i * 16 + ln) * 32 + kq * 8];
#pragma unroll
        for (int j = 0; j < 4; j++)
            bfr[j] = *(const sh8*)&Bl[(wn + j * 16 + ln) * 32 + kq * 8];
#pragma unroll
        for (int i = 0; i < 4; i++)
#pragma unroll
            for (int j = 0; j < 4; j++)
                acc[i][j] = __builtin_amdgcn_mfma_f32_16x16x32_bf16(
                    af[i], bfr[j], acc[i][j], 0, 0, 0);
        __syncthreads();
    }

#pragma unroll
    for (int i = 0; i < 4; i++)
#pragma unroll
        for (int j = 0; j < 4; j++) {
            int col = rowB0 + wn + j * 16 + ln;
            if (col >= N) continue;
            float bv = bias[col];
#pragma unroll
            for (int reg = 0; reg < 4; reg++) {
                int row = rowA0 + wm + i * 16 + kq * 4 + reg;
                float v = acc[i][j][reg] + bv;
                if (gelu) v = 0.5f * v * (1.0f + erff(v * 0.70710678118f));
                if (Cb) Cb[(size_t)row * N + col] = f2b(v);
                if (Cf) Cf[(size_t)row * N + col] = v;
            }
        }
}

// ---------------------------------------------------------------------------
// GRU recurrence v3 — MFMA-batched.
// grid = 8: dir = idx&1, b_base = (idx>>1)*16. 512 threads = 8 waves.
// Per step: hp[16b][384] = h[16b][128] @ Whh^T via 12 chained
// mfma_f32_16x16x32_bf16 per wave (wave w owns cols 16w..16w+16 of all
// three gates, so r/z/n accumulators land in-lane for the same (b,j)).
// Whh lives in VGPRs as bf16 B-fragments (loaded once). h double-buffers
// through LDS [16][136] (272B row stride: 16B-aligned, 2-way bank alias =
// free). One barrier per step. xp/residual prefetched TWO steps ahead via
// ping-pong register sets (loop unrolled by 2). Outputs stored directly
// (16-lane contiguous 32B segments); in-place on hb is safe: step s writes
// row ti(s), reads row ti(s+2), barrier-per-step bounds wave skew < 1 step.
// fp32 hstate kept in registers for the z-blend; only the matvec operand
// passes through bf16 (same precision class as every GEMM in the net).
// ---------------------------------------------------------------------------
struct PF {
    ushort xr[4], xz[4], xn[4], rv[4];
};

#define GRU_PREF(p, TS)                                                       \
    if ((TS) < 512) {                                                         \
        int tq_ = dir ? (511 - (TS)) : (TS);                                  \
        size_t xo_ = (size_t)tq_ * 768;                                       \
        size_t ho_ = (size_t)tq_ * 256;                                       \
        _Pragma("unroll") for (int r_ = 0; r_ < 4; r_++) {                    \
            const ushort* xq_ = xp + xb[r_] + xo_;                            \
            p.xr[r_] = xq_[0];                                                \
            p.xz[r_] = xq_[128];                                              \
            p.xn[r_] = xq_[256];                                              \
            p.rv[r_] = hb[hbase[r_] + ho_];                                   \
        }                                                                     \
    }

#define GRU_STEP(S, p)                                                        \
    {                                                                         \
        float xrf[4], xzf[4], xnf[4], rvf[4];                                 \
        _Pragma("unroll") for (int r_ = 0; r_ < 4; r_++) {                    \
            xrf[r_] = b2f(p.xr[r_]);                                          \
            xzf[r_] = b2f(p.xz[r_]);                                          \
            xnf[r_] = b2f(p.xn[r_]);                                          \
            rvf[r_] = b2f(p.rv[r_]);                                          \
        }                                                                     \
        GRU_PREF(p, (S) + 2);                                                 \
        const ushort* hrd = &hA[(S) & 1][ln][0];                              \
        sh8 a0 = *(const sh8*)&hrd[kq * 8];                                   \
        sh8 a1 = *(const sh8*)&hrd[32 + kq * 8];                              \
        sh8 a2 = *(const sh8*)&hrd[64 + kq * 8];                              \
        sh8 a3 = *(const sh8*)&hrd[96 + kq * 8];                              \
        f32x4 accr = (f32x4){0.f, 0.f, 0.f, 0.f};                             \
        f32x4 accz = accr, accn = accr;                                       \
        accr = __builtin_amdgcn_mfma_f32_16x16x32_bf16(a0, bfrag[0][0], accr, 0, 0, 0); \
        accz = __builtin_amdgcn_mfma_f32_16x16x32_bf16(a0, bfrag[1][0], accz, 0, 0, 0); \
        accn = __builtin_amdgcn_mfma_f32_16x16x32_bf16(a0, bfrag[2][0], accn, 0, 0, 0); \
        accr = __builtin_amdgcn_mfma_f32_16x16x32_bf16(a1, bfrag[0][1], accr, 0, 0, 0); \
        accz = __builtin_amdgcn_mfma_f32_16x16x32_bf16(a1, bfrag[1][1], accz, 0, 0, 0); \
        accn = __builtin_amdgcn_mfma_f32_16x16x32_bf16(a1, bfrag[2][1], accn, 0, 0, 0); \
        accr = __builtin_amdgcn_mfma_f32_16x16x32_bf16(a2, bfrag[0][2], accr, 0, 0, 0); \
        accz = __builtin_amdgcn_mfma_f32_16x16x32_bf16(a2, bfrag[1][2], accz, 0, 0, 0); \
        accn = __builtin_amdgcn_mfma_f32_16x16x32_bf16(a2, bfrag[2][2], accn, 0, 0, 0); \
        accr = __builtin_amdgcn_mfma_f32_16x16x32_bf16(a3, bfrag[0][3], accr, 0, 0, 0); \
        accz = __builtin_amdgcn_mfma_f32_16x16x32_bf16(a3, bfrag[1][3], accz, 0, 0, 0); \
        accn = __builtin_amdgcn_mfma_f32_16x16x32_bf16(a3, bfrag[2][3], accn, 0, 0, 0); \
        int tw_ = dir ? (511 - (S)) : (S);                                    \
        size_t hw_ = (size_t)tw_ * 256;                                       \
        ushort* hwr = &hA[1 - ((S) & 1)][0][0];                               \
        _Pragma("unroll") for (int r_ = 0; r_ < 4; r_++) {                    \
            float rg = sigmf(xrf[r_] + accr[r_] + bh_r);                      \
            float zg = sigmf(xzf[r_] + accz[r_] + bh_z);                      \
            float ng = tanhf2(fmaf(rg, accn[r_] + bh_n, xnf[r_]));            \
            float h = fmaf(zg, hstate[r_] - ng, ng);                          \
            hstate[r_] = h;                                                   \
            hwr[(kq * 4 + r_) * 136 + jcol] = f2b(h);                         \
            hb[hbase[r_] + hw_] = f2b(h + rvf[r_]);                           \
        }                                                                     \
        __syncthreads();                                                      \
    }

__global__ __launch_bounds__(512, 1) void k_gru(const ushort* __restrict__ xp,
                                                const float* __restrict__ Whh_l,
                                                const float* __restrict__ bhh_l,
                                                ushort* __restrict__ hb) {
    __shared__ __align__(16) ushort hA[2][16][136];

    const int t = threadIdx.x;
    const int w = t >> 6, l = t & 63;
    const int ln = l & 15, kq = l >> 4;
    const int jcol = (w << 4) + ln;  // hidden column this lane's C-tile covers
    const int dir = blockIdx.x & 1;
    const int b_base = (blockIdx.x >> 1) << 4;

    const float* Wd = Whh_l + (size_t)dir * 384 * 128;
    const float* bhh_d = bhh_l + dir * 384;

    // Whh B-fragments, bf16, resident in VGPRs for all 512 steps.
    // B-frag layout: lane holds W[row = tilebase + (lane&15)][k = (lane>>4)*8 .. +8]
    sh8 bfrag[3][4];
#pragma unroll
    for (int g = 0; g < 3; g++)
#pragma unroll
        for (int kt = 0; kt < 4; kt++) {
            const float4* wp =
                (const float4*)(Wd + (size_t)(g * 128 + jcol) * 128 + kt * 32 + kq * 8);
            float4 w0 = wp[0], w1 = wp[1];
            uint4 pv;
            pv.x = pack2(w0.x, w0.y);
            pv.y = pack2(w0.z, w0.w);
            pv.z = pack2(w1.x, w1.y);
            pv.w = pack2(w1.z, w1.w);
            bfrag[g][kt] = *(sh8*)&pv;
        }

    const float bh_r = bhh_d[jcol];
    const float bh_z = bhh_d[128 + jcol];
    const float bh_n = bhh_d[256 + jcol];

    // Per-reg global address bases (C row b = kq*4 + reg).
    size_t xb[4], hbase[4];
#pragma unroll
    for (int r = 0; r < 4; r++) {
        size_t rb = (size_t)(b_base + kq * 4 + r) * 512;
        xb[r] = rb * 768 + (size_t)dir * 384 + jcol;
        hbase[r] = rb * 256 + (size_t)dir * 128 + jcol;
    }

    float hstate[4] = {0.f, 0.f, 0.f, 0.f};

    // h0 = 0
    for (int i = t; i < 16 * 136; i += 512) ((ushort*)hA[0])[i] = 0;

    PF pA, pB;
    GRU_PREF(pA, 0);
    GRU_PREF(pB, 1);
    __syncthreads();

    for (int s = 0; s < 512; s += 2) {
        GRU_STEP(s, pA)
        GRU_STEP(s + 1, pB)
    }
}

// ---------------------------------------------------------------------------
// Host launcher. fp32 inputs AND fp32 output; bf16 internally for MFMA.
// Scratch confined to 64 MiB:
//   [0, 48M)  xp (bf16 32768x768) — also hosts embA, then g (16 MiB each)
//   [48,64M)  hb (bf16 32768x256) — W1 out, GRU layers update in place
// ---------------------------------------------------------------------------
extern "C" void kernel_launch(void* const* d_in, const int* in_sizes, int n_in,
                              void* d_out, int out_size, void* d_ws, size_t ws_size,
                              hipStream_t stream) {
    const void* x = d_in[0];
    const float* embed = (const float*)d_in[1];
    const float* W1 = (const float*)d_in[2];
    const float* b1 = (const float*)d_in[3];
    const float* Wih = (const float*)d_in[4];  // [2][2][384][256]
    const float* Whh = (const float*)d_in[5];  // [2][2][384][128]
    const float* bih = (const float*)d_in[6];  // [2][2][384]
    const float* bhh = (const float*)d_in[7];  // [2][2][384]
    const float* W2 = (const float*)d_in[8];
    const float* b2 = (const float*)d_in[9];
    const float* W3 = (const float*)d_in[10];
    const float* b3 = (const float*)d_in[11];

    char* ws = (char*)d_ws;
    ushort* xp = (ushort*)ws;                         // [0, 48M)
    ushort* hb = (ushort*)(ws + 32768ull * 768 * 2);  // [48M, 64M)
    ushort* embA = xp;  // 16 MiB slot, dead after W1 GEMM
    ushort* g = xp;     // reused after last GRU
    int* xflag = (int*)hb;  // transient; dead after k_gather

    // detect x index width, then gather + W1: hb = bf16(embA @ W1^T + b1)
    k_detx<<<1, 256, 0, stream>>>((const uint*)x, xflag);
    k_gather<<<4096, 256, 0, stream>>>(x, embed, xflag, embA);
    k_gemm_bt<<<dim3(256, 2), 256, 0, stream>>>(embA, W1, b1, hb, (float*)0,
                                                32768, 256, 256, 0);

    // layer 0: xp = hb @ Wih[0]^T + bih[0]; GRU updates hb in place
    k_gemm_bt<<<dim3(256, 6), 256, 0, stream>>>(hb, Wih, bih, xp, (float*)0,
                                                32768, 768, 256, 0);
    k_gru<<<8, 512, 0, stream>>>(xp, Whh, bhh, hb);

    // layer 1
    k_gemm_bt<<<dim3(256, 6), 256, 0, stream>>>(hb, Wih + 196608, bih + 768,
                                                xp, (float*)0, 32768, 768, 256, 0);
    k_gru<<<8, 512, 0, stream>>>(xp, Whh + 98304, bhh + 768, hb);

    // head: g = bf16(GELU(hb @ W2^T + b2)); d_out = fp32(g @ W3^T + b3)
    k_gemm_bt<<<dim3(256, 2), 256, 0, stream>>>(hb, W2, b2, g, (float*)0,
                                                32768, 256, 256, 1);
    k_gemm_bt<<<dim3(256, 1), 256, 0, stream>>>(g, W3, b3, (ushort*)0,
                                                (float*)d_out, 32768, 50, 256, 0);
}